// Round 8
// baseline (6328.058 us; speedup 1.0000x reference)
//
#include <hip/hip_runtime.h>

#define B_ 16
#define T_ 2048
#define L_ 512
#define HD 200
#define AT 50

__device__ __forceinline__ float rcp_(float x){ return __builtin_amdgcn_rcpf(x); }
__device__ __forceinline__ float sigf(float x){ return rcp_(1.f + __expf(-x)); }
__device__ __forceinline__ float tanhf_(float x){
  x = fminf(15.f, fmaxf(-15.f, x));
  float e = __expf(-2.f*x);
  return (1.f - e) * rcp_(1.f + e);
}
__device__ __forceinline__ unsigned bf16u(float v){
  unsigned u = __float_as_uint(v);
  u += 0x7FFFu + ((u >> 16) & 1u);
  return u >> 16;
}
__device__ __forceinline__ unsigned long long pkvs(float v, unsigned s){
  return (unsigned long long)__float_as_uint(v) | ((unsigned long long)s << 32);
}
// wave-uniform broadcast from lane l (VALU, per-SIMD — bypasses the LDS pipe)
__device__ __forceinline__ float RL(float v, int l){
  return __uint_as_float(__builtin_amdgcn_readlane(__float_as_uint(v), l));
}

// ---------------- conv fold: E[3][256] ----------------
__global__ void k_prep(const float* __restrict__ conv1, const float* __restrict__ conv1a,
                       const float* __restrict__ conv2, const float* __restrict__ conv3,
                       float* __restrict__ E)
{
  __shared__ float K2s[3*256];
  int tid = threadIdx.x;            // 768 threads
  int k = tid >> 8, co = tid & 255;
  float a = 0.f;
  for (int ci = 0; ci < 256; ++ci)
    a = fmaf(conv1[ci], conv2[(k*256 + ci)*256 + co], a);
  K2s[k*256 + co] = a;
  __syncthreads();
  float b2 = 0.f;
  for (int ci = 0; ci < 256; ++ci)
    b2 = fmaf(K2s[k*256 + ci], conv3[ci*256 + co], b2);
  if (k == 1) b2 += conv1a[co];
  E[k*256 + co] = b2;
}

// ---------------- feat[b,t,256] ----------------
__global__ void k_feat(const float* __restrict__ sig, const float* __restrict__ E,
                       const float* __restrict__ c1ab, float* __restrict__ feat)
{
  int idx = blockIdx.x*256 + threadIdx.x;
  int row = idx >> 6;
  int c4  = (idx & 63) * 4;
  int t = row & (T_-1);
  float sm = (t > 0)     ? sig[row-1] : 0.f;
  float s0 = sig[row];
  float sp = (t < T_-1)  ? sig[row+1] : 0.f;
  float4 e0 = *(const float4*)&E[0*256 + c4];
  float4 e1 = *(const float4*)&E[1*256 + c4];
  float4 e2 = *(const float4*)&E[2*256 + c4];
  float4 bb = *(const float4*)&c1ab[c4];
  float4 r;
  r.x = fmaxf(0.f, fmaf(sm, e0.x, fmaf(s0, e1.x, fmaf(sp, e2.x, bb.x))));
  r.y = fmaxf(0.f, fmaf(sm, e0.y, fmaf(s0, e1.y, fmaf(sp, e2.y, bb.y))));
  r.z = fmaxf(0.f, fmaf(sm, e0.z, fmaf(s0, e1.z, fmaf(sp, e2.z, bb.z))));
  r.w = fmaxf(0.f, fmaf(sm, e0.w, fmaf(s0, e1.w, fmaf(sp, e2.w, bb.w))));
  *(float4*)&feat[(size_t)row*256 + c4] = r;
}

// ---------------- fp32 GEMM, 128x64 tile, 8x4 acc/thread ----------------
__global__ __launch_bounds__(256)
void k_gemm(const float* __restrict__ A, const float* __restrict__ B,
            const float* __restrict__ bias, float* __restrict__ C,
            int M, int N, int K, int ldb)
{
  __shared__ float As[16][132];
  __shared__ float Bs[16][68];
  int row0 = blockIdx.x*128, col0 = blockIdx.y*64;
  int tid = threadIdx.x;
  int tm = tid >> 4, tn = tid & 15;
  float acc[8][4] = {};
  for (int k0 = 0; k0 < K; k0 += 16){
    #pragma unroll
    for (int i = 0; i < 8; ++i){
      int e = tid + i*256;
      int m = e >> 4, kk = e & 15;
      float v = 0.f;
      if (k0 + kk < K) v = A[(size_t)(row0+m)*K + k0 + kk];
      As[kk][m] = v;
    }
    #pragma unroll
    for (int i = 0; i < 4; ++i){
      int e = tid + i*256;
      int n = e & 63, kb = e >> 6;
      float w = 0.f;
      if (k0 + kb < K && col0 + n < N) w = B[(size_t)(k0+kb)*ldb + col0 + n];
      Bs[kb][n] = w;
    }
    __syncthreads();
    #pragma unroll
    for (int kk = 0; kk < 16; ++kk){
      float a[8], bv[4];
      *(float4*)&a[0] = *(const float4*)&As[kk][tm*8];
      *(float4*)&a[4] = *(const float4*)&As[kk][tm*8+4];
      *(float4*)&bv[0] = *(const float4*)&Bs[kk][tn*4];
      #pragma unroll
      for (int i = 0; i < 8; ++i)
        #pragma unroll
        for (int j = 0; j < 4; ++j)
          acc[i][j] = fmaf(a[i], bv[j], acc[i][j]);
    }
    __syncthreads();
  }
  #pragma unroll
  for (int i = 0; i < 8; ++i){
    int r = row0 + tm*8 + i;
    #pragma unroll
    for (int j = 0; j < 4; ++j){
      int cc = col0 + tn*4 + j;
      if (cc < N) C[(size_t)r*N + cc] = acc[i][j] + (bias ? bias[cc] : 0.f);
    }
  }
}

// ---------------- weight permute for quad-gate encoder layout ----------------
__global__ void k_permW(const float* __restrict__ Wf, const float* __restrict__ bf,
                        const float* __restrict__ Wb, const float* __restrict__ bb,
                        float* __restrict__ WpF, float* __restrict__ WpB)
{
  int idx = blockIdx.x*256 + threadIdx.x;
  if (idx >= 2*357*400) return;
  int w = idx / (357*400), r = idx - w*(357*400);
  int j = r / 400, col = r - j*400;
  int src = (col & 3)*100 + (col >> 2);
  const float* W = w ? Wb : Wf; const float* bs = w ? bb : bf;
  float v = (j < 356) ? W[j*400 + src] : bs[src];
  (w ? WpB : WpF)[j*400 + col] = v;
}

// ---------------- standalone encoder (small-ws fallback path only) ----------------
__global__ __launch_bounds__(512, 1)
void k_encoder(const float* __restrict__ xprojF, const float* __restrict__ xprojB,
               const float* __restrict__ WpF, const float* __restrict__ WpB,
               const int* __restrict__ sig_len, float* __restrict__ memory,
               float* __restrict__ c0h0, int dirParam)
{
  int dir = dirParam, b = blockIdx.x;
  const float* xp = dir ? xprojB : xprojF;
  const float* Wp = dir ? WpB : WpF;
  int tid = threadIdx.x;
  bool act = tid < 400;
  int col = act ? tid : (tid - 400);
  int u = tid >> 2, gq = tid & 3;
  __shared__ __align__(16) float h2[2][104];
  float4 Uv[25];
  #pragma unroll
  for (int j4 = 0; j4 < 25; ++j4){
    Uv[j4].x = Wp[(256 + 4*j4 + 0)*400 + col];
    Uv[j4].y = Wp[(256 + 4*j4 + 1)*400 + col];
    Uv[j4].z = Wp[(256 + 4*j4 + 2)*400 + col];
    Uv[j4].w = Wp[(256 + 4*j4 + 3)*400 + col];
  }
  if (tid < 100) h2[0][tid] = 0.f;
  int len = sig_len[b];
  float c = 0.f, hfin = 0.f;
  int ta = dir ? (len-1) : 0;
  float xb0 = xp[((size_t)(b*T_ + ta))*400 + col];
  int tb_ = dir ? (len-2) : 1;
  float xb1 = xp[((size_t)(b*T_ + tb_))*400 + col];
  for (int step = 0; step < len; ++step){
    __syncthreads();
    int tn = dir ? (len-3-step) : (step+2);
    tn = tn < 0 ? 0 : (tn > T_-1 ? T_-1 : tn);
    float xn = xp[((size_t)(b*T_ + tn))*400 + col];
    const float* hb = h2[step & 1];
    float a0 = xb0, a1 = 0.f, a2 = 0.f, a3 = 0.f;
    #pragma unroll
    for (int j4 = 0; j4 < 25; ++j4){
      float4 h4 = *(const float4*)&hb[j4*4];
      a0 = fmaf(h4.x, Uv[j4].x, a0);
      a1 = fmaf(h4.y, Uv[j4].y, a1);
      a2 = fmaf(h4.z, Uv[j4].z, a2);
      a3 = fmaf(h4.w, Uv[j4].w, a3);
    }
    float z = (a0+a1)+(a2+a3);
    float v0 = z, v1 = __shfl_xor(z, 1);
    float v2 = __shfl_xor(v0, 2), v3 = __shfl_xor(v1, 2);
    float tA  = (gq&1) ? v1 : v0, tB  = (gq&1) ? v3 : v2;
    float tA2 = (gq&1) ? v0 : v1, tB2 = (gq&1) ? v2 : v3;
    float zi = (gq&2) ? tB  : tA;
    float zj = (gq&2) ? tB2 : tA2;
    float zf = (gq&2) ? tA  : tB;
    float zo = (gq&2) ? tA2 : tB2;
    c = c*sigf(zf + 1.f) + sigf(zi)*tanhf_(zj);
    float nh = tanhf_(c)*sigf(zo);
    hfin = nh;
    if (act && gq == 0){
      int t = dir ? (len-1-step) : step;
      h2[(step+1)&1][u] = nh;
      memory[((size_t)(b*T_ + t))*200 + dir*100 + u] = nh;
    }
    xb0 = xb1; xb1 = xn;
  }
  if (act && gq == 0){
    c0h0[b*400 + dir*100 + u]       = c;
    c0h0[b*400 + 200 + dir*100 + u] = hfin;
  }
  int total = (T_ - len)*100;
  for (int i = tid; i < total; i += 512){
    int t = len + i/100;
    int k = i - (i/100)*100;
    memory[((size_t)(b*T_ + t))*200 + dir*100 + k] = 0.f;
  }
}

// ---------------- decoder input gather ----------------
__global__ void k_gather(const float* __restrict__ emb, const int* __restrict__ labels,
                         float* __restrict__ dA)
{
  int idx = blockIdx.x*256 + threadIdx.x;
  int i = idx >> 6, e = idx & 63;
  dA[(size_t)i*64 + e] = emb[labels[i]*64 + e];
}

// ---------------- init: zero out + seq slots + flags ----------------
__global__ void k_dec_init(unsigned long long* __restrict__ nhb,
                           unsigned long long* __restrict__ parts,
                           unsigned* __restrict__ flags, unsigned fval,
                           float* __restrict__ out)
{
  int idx = blockIdx.x*256 + threadIdx.x;   // grid 192 -> 49152
  if (idx < B_*L_*6) out[idx] = 0.f;
  if (idx < B_*HD) nhb[idx] = 0ull;
  if (idx < B_*16*112) parts[idx] = 0ull;
  if (idx < 32) flags[idx] = fval;
}

// ================= fused encoder + keys + decoder =================
#define DEC_LDS 137728
#define TCH 128

__global__ __launch_bounds__(256)
__attribute__((amdgpu_waves_per_eu(1, 1)))
void k_fused(const float* __restrict__ xprojF, const float* __restrict__ xprojB,
             const float* __restrict__ WpF, const float* __restrict__ WpB,
             float* __restrict__ memG, float* c0h0,
             const float* __restrict__ W_mem, const float* __restrict__ W_attn,
             const float* __restrict__ decx, const float* __restrict__ W_dec,
             const float* __restrict__ W_out,
             const int* __restrict__ sig_len, const int* __restrict__ base_len,
             unsigned long long* nhb, unsigned long long* partials,
             unsigned* flags, int encInside,
             float* __restrict__ out)
{
  int blk = blockIdx.x;
  int b = (blk & 7) | (((blk >> 3) & 1) << 3);   // b's 16 blocks -> same XCD
  int g = blk >> 4;
  int tid = threadIdx.x;
  int u0 = g * 13;
  int nu = (HD - u0 < 13) ? (HD - u0) : 13;
  int t0 = g * TCH;

  extern __shared__ char smem[];
  uint2* keyP  = (uint2*)(smem);                 // [p<50][t<128+pad] stride 129
  float* memAL = (float*)(smem + 51616);         // [128][50]
  float* Uld   = (float*)(smem + 77216);         // staging region (stg)
  float* Wa1s  = (float*)(smem + 129216);        // [13][50]
  float* WoutL = (float*)(smem + 131824);        // [50][6]
  float* nhF   = (float*)(smem + 133024);        // [208]
  float* spL   = (float*)(smem + 133856);        // [256]; doubles as encoder h2[2][128]
  float* wL    = (float*)(smem + 134880);        // [128]
  float* cpL   = (float*)(smem + 135392);        // [3][52]
  float* apL   = (float*)(smem + 136016);        // [52]
  float* zp    = (float*)(smem + 136224);        // [52][4]
  float* attnL = (float*)(smem + 137056);        // [52]
  float* SL    = (float*)(smem + 137264);        // [2]
  float* ctxR  = (float*)(smem + 137272);        // [52]
  float* apR   = (float*)(smem + 137480);        // [52]

  // ================= phase E: encoder (blocks g<2) =================
  if (encInside && g < 2){
    int dir = g;
    const float* xp = dir ? xprojB : xprojF;
    const float* Wp = dir ? WpB : WpF;
    float* WL2 = (float*)smem;          // [25][144][4] col2 weights (57.6 KB)
    float* h2  = spL;                   // [2][128]
    for (int i = tid; i < 25*144*4; i += 256){
      int j4 = i / 576, r = i - j4*576;
      WL2[i] = Wp[(256 + 4*j4 + (r & 3))*400 + 256 + (r >> 2)];
    }
    h2[tid] = 0.f;                      // zero both buffers (256 floats)
    // col1 weights in regs (100 VGPR)
    float U1[100];
    #pragma unroll
    for (int j = 0; j < 100; ++j) U1[j] = Wp[(256 + j)*400 + tid];
    int len = sig_len[b];
    int gq = tid & 3;
    bool has2 = tid < 144;
    int col2 = 256 + (has2 ? tid : 0);
    int lane = tid & 63;
    float c1 = 0.f, c2v = 0.f, hf1 = 0.f, hf2 = 0.f;
    int taa = dir ? (len-1) : 0;
    int tbb = dir ? (len-2) : 1;
    float xA0 = xp[((size_t)(b*T_ + taa))*400 + tid];
    float xA1 = xp[((size_t)(b*T_ + tbb))*400 + tid];
    float xB0 = has2 ? xp[((size_t)(b*T_ + taa))*400 + col2] : 0.f;
    float xB1 = has2 ? xp[((size_t)(b*T_ + tbb))*400 + col2] : 0.f;
    for (int step = 0; step < len; ++step){
      __syncthreads();
      int tn = dir ? (len-3-step) : (step+2);
      tn = tn < 0 ? 0 : (tn > T_-1 ? T_-1 : tn);
      float xA2 = xp[((size_t)(b*T_ + tn))*400 + tid];
      float xB2 = has2 ? xp[((size_t)(b*T_ + tn))*400 + col2] : 0.f;
      const float* hb = h2 + (step & 1)*128;
      float hr0 = hb[lane];
      float hr1 = hb[64 + lane];
      // z1: readlane broadcast + reg weights (VALU only)
      float z1 = xA0;
      #pragma unroll
      for (int j = 0; j < 100; ++j)
        z1 = fmaf((j < 64) ? RL(hr0, j) : RL(hr1, j - 64), U1[j], z1);
      // z2: LDS b128 weights (only 2.25 waves execute)
      float z2 = xB0;
      if (has2){
        #pragma unroll
        for (int j4 = 0; j4 < 25; ++j4){
          float4 w2 = *(const float4*)&WL2[(j4*144 + tid)*4];
          int j = j4*4;
          z2 = fmaf((j   < 64) ? RL(hr0, j  ) : RL(hr1, j-64),   w2.x, z2);
          z2 = fmaf((j+1 < 64) ? RL(hr0, j+1) : RL(hr1, j-63),   w2.y, z2);
          z2 = fmaf((j+2 < 64) ? RL(hr0, j+2) : RL(hr1, j-62),   w2.z, z2);
          z2 = fmaf((j+3 < 64) ? RL(hr0, j+3) : RL(hr1, j-61),   w2.w, z2);
        }
      }
      // quad all-gather for z1
      float v0 = z1, v1 = __shfl_xor(z1, 1);
      float v2 = __shfl_xor(v0, 2), v3 = __shfl_xor(v1, 2);
      float tA  = (gq&1) ? v1 : v0, tB  = (gq&1) ? v3 : v2;
      float tA2 = (gq&1) ? v0 : v1, tB2 = (gq&1) ? v2 : v3;
      float zi = (gq&2) ? tB : tA,  zj = (gq&2) ? tB2 : tA2;
      float zf = (gq&2) ? tA : tB,  zo = (gq&2) ? tA2 : tB2;
      c1 = c1*sigf(zf + 1.f) + sigf(zi)*tanhf_(zj);
      float nh1 = tanhf_(c1)*sigf(zo);
      hf1 = nh1;
      // quad all-gather for z2
      float w0 = z2, w1 = __shfl_xor(z2, 1);
      float w2s = __shfl_xor(w0, 2), w3 = __shfl_xor(w1, 2);
      tA  = (gq&1) ? w1 : w0;  tB  = (gq&1) ? w3 : w2s;
      tA2 = (gq&1) ? w0 : w1;  tB2 = (gq&1) ? w2s : w3;
      zi = (gq&2) ? tB : tA;   zj = (gq&2) ? tB2 : tA2;
      zf = (gq&2) ? tA : tB;   zo = (gq&2) ? tA2 : tB2;
      c2v = c2v*sigf(zf + 1.f) + sigf(zi)*tanhf_(zj);
      float nh2 = tanhf_(c2v)*sigf(zo);
      hf2 = nh2;
      float* hn = h2 + ((step+1)&1)*128;
      if (gq == 0){
        int t = dir ? (len-1-step) : step;
        int u1 = tid >> 2;
        hn[u1] = nh1;
        memG[((size_t)(b*T_ + t))*200 + dir*100 + u1] = nh1;
        if (has2){
          hn[64 + u1] = nh2;
          memG[((size_t)(b*T_ + t))*200 + dir*100 + 64 + u1] = nh2;
        }
      }
      xA0 = xA1; xA1 = xA2; xB0 = xB1; xB1 = xB2;
    }
    if ((tid & 3) == 0){
      int u1 = tid >> 2;
      c0h0[b*400 + dir*100 + u1]       = c1;
      c0h0[b*400 + 200 + dir*100 + u1] = hf1;
      if (has2){
        c0h0[b*400 + dir*100 + 64 + u1]       = c2v;
        c0h0[b*400 + 200 + dir*100 + 64 + u1] = hf2;
      }
    }
    int total = (T_ - len)*100;
    for (int i = tid; i < total; i += 256){
      int t = len + i/100;
      int k = i - (i/100)*100;
      memG[((size_t)(b*T_ + t))*200 + dir*100 + k] = 0.f;
    }
    __syncthreads();
    if (tid == 0){
      __builtin_amdgcn_fence(__ATOMIC_RELEASE, "agent");
      __hip_atomic_store(&flags[b*2 + dir], 1u,
                         __ATOMIC_RELAXED, __HIP_MEMORY_SCOPE_AGENT);
    }
  }

  // ================= wait for encoder-b done =================
  if (encInside){
    if (tid == 0){
      while (__hip_atomic_load(&flags[b*2+0], __ATOMIC_RELAXED, __HIP_MEMORY_SCOPE_AGENT) == 0u)
        __builtin_amdgcn_s_sleep(8);
      while (__hip_atomic_load(&flags[b*2+1], __ATOMIC_RELAXED, __HIP_MEMORY_SCOPE_AGENT) == 0u)
        __builtin_amdgcn_s_sleep(8);
      __builtin_amdgcn_fence(__ATOMIC_ACQUIRE, "agent");
    }
    __syncthreads();
  }

  // ================= keys + memA for this block's t-chunk =================
  unsigned* stg = (unsigned*)Uld;       // [t<128][p2<100] bf16x2
  for (int i = tid; i < TCH*100; i += 256){
    int t = i / 100, p2 = i - (i/100)*100;
    float2 mv = *(const float2*)&memG[((size_t)(b*T_ + t0 + t))*200 + 2*p2];
    stg[i] = bf16u(mv.x) | (bf16u(mv.y) << 16);
  }
  __syncthreads();
  {
    int t = tid >> 1, dh = tid & 1;     // 2 threads per t
    const unsigned* mrow = stg + t*100;
    for (int dq = 0; dq < 25; ++dq){
      int d = dh*100 + dq*4;
      float ax = 0.f, ay = 0.f, az = 0.f, aw = 0.f;
      for (int p2 = 0; p2 < 100; ++p2){
        unsigned mm = mrow[p2];
        float m0 = __uint_as_float(mm << 16);
        float m1 = __uint_as_float(mm & 0xFFFF0000u);
        float4 w0 = *(const float4*)&W_mem[(size_t)(2*p2)*200 + d];
        float4 w1 = *(const float4*)&W_mem[(size_t)(2*p2+1)*200 + d];
        ax = fmaf(m0, w0.x, fmaf(m1, w1.x, ax));
        ay = fmaf(m0, w0.y, fmaf(m1, w1.y, ay));
        az = fmaf(m0, w0.z, fmaf(m1, w1.z, az));
        aw = fmaf(m0, w0.w, fmaf(m1, w1.w, aw));
      }
      keyP[(d>>2)*129 + t] = make_uint2(bf16u(ax) | (bf16u(ay) << 16),
                                        bf16u(az) | (bf16u(aw) << 16));
    }
    for (int dd = 0; dd < 25; ++dd){
      int d = dh*25 + dd;
      float acc = 0.f;
      for (int p2 = 0; p2 < 100; ++p2){
        unsigned mm = mrow[p2];
        float m0 = __uint_as_float(mm << 16);
        float m1 = __uint_as_float(mm & 0xFFFF0000u);
        acc = fmaf(m0, W_attn[(size_t)(200 + 2*p2)*50 + d],
              fmaf(m1, W_attn[(size_t)(201 + 2*p2)*50 + d], acc));
      }
      memAL[t*50 + d] = acc;
    }
  }

  // ================= one-time decoder fills =================
  int oL = tid & 63;
  int jc = tid >> 6;                    // wave-uniform
  int uu = oL >> 2, gg = oL & 3;
  bool vOK = (oL < 52) && (uu < nu);
  int uuC = (uu < nu ? uu : 0);
  // loop-invariant gemv weights -> registers
  float Uh[50], Ua[13];
  #pragma unroll
  for (int j = 0; j < 50; ++j){
    float v = W_dec[(size_t)(114 + jc*50 + j)*800 + gg*200 + u0 + uuC];
    Uh[j] = vOK ? v : 0.f;
  }
  #pragma unroll
  for (int j = 0; j < 13; ++j){
    float v = W_dec[(size_t)(64 + jc*13 + j)*800 + gg*200 + u0 + uuC];
    Ua[j] = vOK ? v : 0.f;
  }
  for (int i = tid; i < 13*50; i += 256){
    int uw = i / 50, d = i - (i/50)*50;
    Wa1s[i] = (uw < nu) ? W_attn[(size_t)(u0 + uw)*50 + d] : 0.f;
  }
  for (int i = tid; i < 300; i += 256) WoutL[i] = W_out[i];
  if (tid < 52) attnL[tid] = 0.f;       // [50],[51] stay 0 (readlane padding)
  if (tid < 8)  nhF[200 + tid] = 0.f;
  float creg = (tid < nu) ? c0h0[b*400 + u0 + tid] : 0.f;
  int len = sig_len[b];
  int Lb  = base_len[b];
  unsigned long long* nhB = nhb + (size_t)b*HD;
  __syncthreads();

  // memA chunk -> registers (loop-invariant); zero-pad tail
  float Mw[43];
  {
    int dF = (oL < 50) ? oL : 49;
    #pragma unroll
    for (int i = 0; i < 43; ++i){
      int t = jc*43 + i;
      float v = memAL[((t < 128) ? t : 127)*50 + dF];
      Mw[i] = (t < 128) ? v : 0.f;
    }
  }

  // ---- pre-loop: nhF = h0; zh(0); dcx(0) ----
  if (tid < 50) *(float4*)&nhF[tid*4] = *(const float4*)&c0h0[b*400 + 200 + tid*4];
  __syncthreads();
  float zh = 0.f, dcx = 0.f;
  {
    float hrg = nhF[jc*50 + oL];
    #pragma unroll
    for (int j = 0; j < 50; ++j) zh = fmaf(RL(hrg, j), Uh[j], zh);
    if (jc == 0 && oL < 52)
      dcx = decx[((size_t)(b*L_))*800 + (oL&3)*200 + u0 + (oL>>2)];
  }

  for (int l = 0; l < Lb; ++l){
    unsigned seq = (unsigned)(l + 1);
    // ---- A: za gemv via readlane; g1 lanes 52..57 write out(l-1)
    if (oL < 52){
      float ar = attnL[jc*13 + oL];
      float z = zh + ((jc == 0) ? dcx : 0.f);
      #pragma unroll
      for (int j = 0; j < 13; ++j) z = fmaf(RL(ar, j), Ua[j], z);
      zp[oL*4 + jc] = z;
    } else if (g == 1 && l > 0 && tid >= 52 && tid < 58){
      int j = tid - 52;
      float o_ = 0.f;
      for (int d = 0; d < AT; ++d) o_ = fmaf(attnL[d], WoutL[d*6 + j], o_);
      out[((size_t)(b*L_ + (l-1)))*6 + j] = o_;
    }
    __syncthreads();
    // ---- B: combine + activation; publish nh slice
    if (tid < nu){
      const float* zz = &zp[(4*tid)*4];
      float zi = (zz[0]+zz[1])+(zz[2]+zz[3]);
      float zj = (zz[4]+zz[5])+(zz[6]+zz[7]);
      float zf = (zz[8]+zz[9])+(zz[10]+zz[11]);
      float zo = (zz[12]+zz[13])+(zz[14]+zz[15]);
      float c = creg;
      c = c*sigf(zf + 1.f) + sigf(zi)*tanhf_(zj);
      creg = c;
      float nh = tanhf_(c)*sigf(zo);
      __hip_atomic_store(&nhB[u0 + tid], pkvs(nh, seq),
                         __ATOMIC_RELAXED, __HIP_MEMORY_SCOPE_AGENT);
    }
    // ---- C: poll full nh vector
    if (tid < HD){
      unsigned long long v;
      do {
        v = __hip_atomic_load(&nhB[tid], __ATOMIC_RELAXED, __HIP_MEMORY_SCOPE_AGENT);
      } while ((unsigned)(v >> 32) != seq);
      nhF[tid] = __uint_as_float((unsigned)v);
    }
    __syncthreads();
    // ---- D: scores over t-chunk (bf16 keys, conflict-free)
    {
      int t = tid & 127, dh = tid >> 7;
      const uint2* kp = &keyP[(dh*25)*129 + t];
      const float4* nf = (const float4*)nhF + dh*25;
      float s0 = 0.f, s1 = 0.f;
      #pragma unroll
      for (int q = 0; q < 25; ++q){
        uint2 kk = kp[(size_t)q*129];
        float4 nv = nf[q];
        s0 = fmaf(nv.x, __uint_as_float(kk.x << 16), s0);
        s1 = fmaf(nv.y, __uint_as_float(kk.x & 0xFFFF0000u), s1);
        s0 = fmaf(nv.z, __uint_as_float(kk.y << 16), s0);
        s1 = fmaf(nv.w, __uint_as_float(kk.y & 0xFFFF0000u), s1);
      }
      spL[tid] = s0 + s1;
    }
    __syncthreads();
    // ---- E: w=exp ; ap gemv
    if (tid < 128){
      float s = spL[tid] + spL[tid + 128];
      float w = 0.f;
      if (t0 + tid < len){ s = fminf(60.f, fmaxf(-60.f, s)); w = __expf(s); }
      wL[tid] = w;
    } else if (tid < 178){
      int d = tid - 128;
      float a = 0.f;
      #pragma unroll
      for (int uw = 0; uw < 13; ++uw) a = fmaf(nhF[u0 + uw], Wa1s[uw*50 + d], a);
      apL[d] = a;
    }
    __syncthreads();
    // ---- F: ctx partials (readlane w + reg memA) + S reduce
    if (tid >= 192){
      float v = wL[tid - 192] + wL[tid - 128];
      #pragma unroll
      for (int off = 32; off > 0; off >>= 1) v += __shfl_down(v, off);
      if (tid == 192) SL[0] = v;
    } else {
      float wr = wL[jc*43 + oL];
      float a = 0.f;
      #pragma unroll
      for (int i = 0; i < 43; ++i) a = fmaf(RL(wr, i), Mw[i], a);
      if (oL < 50) cpL[jc*52 + oL] = a;
    }
    __syncthreads();
    // ---- G: publish partials; zh(l+1)+dcx(l+1); poll-reduce partials
    {
      unsigned long long* pb = partials + (size_t)(b*16 + g)*112;
      if (tid < 50)
        __hip_atomic_store(&pb[tid],
                           pkvs((cpL[tid] + cpL[52 + tid]) + cpL[104 + tid], seq),
                           __ATOMIC_RELAXED, __HIP_MEMORY_SCOPE_AGENT);
      else if (tid < 100)
        __hip_atomic_store(&pb[tid], pkvs(apL[tid - 50], seq),
                           __ATOMIC_RELAXED, __HIP_MEMORY_SCOPE_AGENT);
      else if (tid == 100)
        __hip_atomic_store(&pb[100], pkvs(SL[0], seq),
                           __ATOMIC_RELAXED, __HIP_MEMORY_SCOPE_AGENT);
    }
    zh = 0.f;
    {
      float hrg = nhF[jc*50 + oL];
      #pragma unroll
      for (int j = 0; j < 50; ++j) zh = fmaf(RL(hrg, j), Uh[j], zh);
      if (jc == 0 && oL < 52 && l+1 < Lb)
        dcx = decx[((size_t)(b*L_ + (l+1)))*800 + (oL&3)*200 + u0 + (oL>>2)];
    }
    if (tid < 101){
      const unsigned long long* base = partials + (size_t)b*16*112 + tid;
      unsigned long long v[16];
      #pragma unroll
      for (int gq2 = 0; gq2 < 16; ++gq2)
        v[gq2] = __hip_atomic_load(&base[gq2*112], __ATOMIC_RELAXED, __HIP_MEMORY_SCOPE_AGENT);
      #pragma unroll
      for (int gq2 = 0; gq2 < 16; ++gq2)
        while ((unsigned)(v[gq2] >> 32) != seq)
          v[gq2] = __hip_atomic_load(&base[gq2*112], __ATOMIC_RELAXED, __HIP_MEMORY_SCOPE_AGENT);
      float acc = 0.f;
      #pragma unroll
      for (int gq2 = 0; gq2 < 16; ++gq2) acc += __uint_as_float((unsigned)v[gq2]);
      if (tid < 50) ctxR[tid] = acc;
      else if (tid < 100) apR[tid - 50] = acc;
      else SL[1] = acc;
    }
    __syncthreads();
    // ---- H: attn(l)
    if (tid < 50) attnL[tid] = fmaf(ctxR[tid], rcp_(SL[1]), apR[tid]);
    __syncthreads();
  }
  // tail: out(Lb-1)
  if (g == 1 && tid < 6){
    float o_ = 0.f;
    for (int d = 0; d < AT; ++d) o_ = fmaf(attnL[d], WoutL[d*6 + tid], o_);
    out[((size_t)(b*L_ + (Lb-1)))*6 + tid] = o_;
  }
}

extern "C" void kernel_launch(void* const* d_in, const int* in_sizes, int n_in,
                              void* d_out, int out_size, void* d_ws, size_t ws_size,
                              hipStream_t stream)
{
  const float* signals   = (const float*)d_in[0];
  const float* embeddings= (const float*)d_in[1];
  const float* conv1_k   = (const float*)d_in[2];
  const float* conv1a_k  = (const float*)d_in[3];
  const float* conv1a_b  = (const float*)d_in[4];
  const float* conv2_k   = (const float*)d_in[5];
  const float* conv3_k   = (const float*)d_in[6];
  const float* W_fwd     = (const float*)d_in[7];
  const float* b_fwd     = (const float*)d_in[8];
  const float* W_bwd     = (const float*)d_in[9];
  const float* b_bwd     = (const float*)d_in[10];
  const float* W_dec     = (const float*)d_in[11];
  const float* b_dec     = (const float*)d_in[12];
  const float* W_mem     = (const float*)d_in[13];
  const float* W_attn    = (const float*)d_in[14];
  const float* W_out     = (const float*)d_in[15];
  const int*   labels    = (const int*)d_in[16];
  const int*   sig_len   = (const int*)d_in[17];
  const int*   base_len  = (const int*)d_in[18];
  float* out = (float*)d_out;
  char* ws = (char*)d_ws;

  const size_t o_c0h0     = 4096;
  const size_t o_nhbuf    = 32768;
  const size_t o_partials = 65536;
  const size_t o_flags    = 458752;
  const size_t o_WpF      = 589824;
  const size_t o_WpB      = 1161024;
  const size_t o_feat     = 4194304;
  const size_t o_mem      = o_feat + 33554432;
  const size_t o_X1       = o_mem + 26214400;
  const size_t o_X2       = o_X1 + 52428800;

  bool bigws = (ws_size >= o_X2 + 52428800);

  float* E      = (float*)(ws);
  float* c0h0   = (float*)(ws + o_c0h0);
  unsigned long long* nhbuf = (unsigned long long*)(ws + o_nhbuf);
  unsigned long long* parts = (unsigned long long*)(ws + o_partials);
  unsigned* flags = (unsigned*)(ws + o_flags);
  float* WpF    = (float*)(ws + o_WpF);
  float* WpB    = (float*)(ws + o_WpB);
  float* feat   = (float*)(ws + o_feat);
  float* memory = (float*)(ws + o_mem);
  float* xprojF = (float*)(ws + o_X1);
  float* xprojB = bigws ? (float*)(ws + o_X2) : xprojF;
  float* decxA  = (float*)(ws + o_feat);                 // overlay (feat dead)
  float* decx   = (float*)(ws + o_feat + 4194304);       // overlay (feat dead)

  k_prep<<<1, 768, 0, stream>>>(conv1_k, conv1a_k, conv2_k, conv3_k, E);
  k_feat<<<8192, 256, 0, stream>>>(signals, E, conv1a_b, feat);
  k_permW<<<1116, 256, 0, stream>>>(W_fwd, b_fwd, W_bwd, b_bwd, WpF, WpB);

  dim3 gx(256, 7);
  if (bigws){
    k_gemm<<<gx, 256, 0, stream>>>(feat, WpF, WpF + 356*400, xprojF, 32768, 400, 256, 400);
    k_gemm<<<gx, 256, 0, stream>>>(feat, WpB, WpB + 356*400, xprojB, 32768, 400, 256, 400);
  } else {
    k_gemm<<<gx, 256, 0, stream>>>(feat, WpF, WpF + 356*400, xprojF, 32768, 400, 256, 400);
    k_encoder<<<16, 512, 0, stream>>>(xprojF, xprojF, WpF, WpB, sig_len, memory, c0h0, 0);
    k_gemm<<<gx, 256, 0, stream>>>(feat, WpB, WpB + 356*400, xprojF, 32768, 400, 256, 400);
    k_encoder<<<16, 512, 0, stream>>>(xprojF, xprojF, WpF, WpB, sig_len, memory, c0h0, 1);
  }

  // feat dead now -> decxA/decx overlay safe
  k_gather<<<2048, 256, 0, stream>>>(embeddings, labels, decxA);
  k_gemm<<<dim3(64, 13), 256, 0, stream>>>(decxA, W_dec, b_dec, decx, 8192, 800, 64, 800);
  k_dec_init<<<192, 256, 0, stream>>>(nhbuf, parts, flags, bigws ? 0u : 1u, out);

  hipFuncSetAttribute(reinterpret_cast<const void*>(k_fused),
                      hipFuncAttributeMaxDynamicSharedMemorySize, DEC_LDS);
  k_fused<<<256, 256, DEC_LDS, stream>>>(xprojF, xprojB, WpF, WpB,
                                         memory, c0h0, W_mem, W_attn,
                                         decx, W_dec, W_out,
                                         sig_len, base_len,
                                         nhbuf, parts, flags, bigws ? 1 : 0,
                                         out);
}

// Round 9
// 4347.947 us; speedup vs baseline: 1.4554x; 1.4554x over previous
//
#include <hip/hip_runtime.h>

#define B_ 16
#define T_ 2048
#define L_ 512
#define HD 200
#define AT 50

__device__ __forceinline__ float rcp_(float x){ return __builtin_amdgcn_rcpf(x); }
__device__ __forceinline__ float sigf(float x){ return rcp_(1.f + __expf(-x)); }
__device__ __forceinline__ float tanhf_(float x){
  x = fminf(15.f, fmaxf(-15.f, x));
  float e = __expf(-2.f*x);
  return (1.f - e) * rcp_(1.f + e);
}
__device__ __forceinline__ unsigned bf16u(float v){
  unsigned u = __float_as_uint(v);
  u += 0x7FFFu + ((u >> 16) & 1u);
  return u >> 16;
}
__device__ __forceinline__ unsigned long long pkvs(float v, unsigned s){
  return (unsigned long long)__float_as_uint(v) | ((unsigned long long)s << 32);
}

// ---------------- conv fold: E[3][256] ----------------
__global__ void k_prep(const float* __restrict__ conv1, const float* __restrict__ conv1a,
                       const float* __restrict__ conv2, const float* __restrict__ conv3,
                       float* __restrict__ E)
{
  __shared__ float K2s[3*256];
  int tid = threadIdx.x;            // 768 threads
  int k = tid >> 8, co = tid & 255;
  float a = 0.f;
  for (int ci = 0; ci < 256; ++ci)
    a = fmaf(conv1[ci], conv2[(k*256 + ci)*256 + co], a);
  K2s[k*256 + co] = a;
  __syncthreads();
  float b2 = 0.f;
  for (int ci = 0; ci < 256; ++ci)
    b2 = fmaf(K2s[k*256 + ci], conv3[ci*256 + co], b2);
  if (k == 1) b2 += conv1a[co];
  E[k*256 + co] = b2;
}

// ---------------- feat[b,t,256] ----------------
__global__ void k_feat(const float* __restrict__ sig, const float* __restrict__ E,
                       const float* __restrict__ c1ab, float* __restrict__ feat)
{
  int idx = blockIdx.x*256 + threadIdx.x;
  int row = idx >> 6;
  int c4  = (idx & 63) * 4;
  int t = row & (T_-1);
  float sm = (t > 0)     ? sig[row-1] : 0.f;
  float s0 = sig[row];
  float sp = (t < T_-1)  ? sig[row+1] : 0.f;
  float4 e0 = *(const float4*)&E[0*256 + c4];
  float4 e1 = *(const float4*)&E[1*256 + c4];
  float4 e2 = *(const float4*)&E[2*256 + c4];
  float4 bb = *(const float4*)&c1ab[c4];
  float4 r;
  r.x = fmaxf(0.f, fmaf(sm, e0.x, fmaf(s0, e1.x, fmaf(sp, e2.x, bb.x))));
  r.y = fmaxf(0.f, fmaf(sm, e0.y, fmaf(s0, e1.y, fmaf(sp, e2.y, bb.y))));
  r.z = fmaxf(0.f, fmaf(sm, e0.z, fmaf(s0, e1.z, fmaf(sp, e2.z, bb.z))));
  r.w = fmaxf(0.f, fmaf(sm, e0.w, fmaf(s0, e1.w, fmaf(sp, e2.w, bb.w))));
  *(float4*)&feat[(size_t)row*256 + c4] = r;
}

// ---------------- fp32 GEMM, 128x64 tile, 8x4 acc/thread ----------------
__global__ __launch_bounds__(256)
void k_gemm(const float* __restrict__ A, const float* __restrict__ B,
            const float* __restrict__ bias, float* __restrict__ C,
            int M, int N, int K, int ldb)
{
  __shared__ float As[16][132];
  __shared__ float Bs[16][68];
  int row0 = blockIdx.x*128, col0 = blockIdx.y*64;
  int tid = threadIdx.x;
  int tm = tid >> 4, tn = tid & 15;
  float acc[8][4] = {};
  for (int k0 = 0; k0 < K; k0 += 16){
    #pragma unroll
    for (int i = 0; i < 8; ++i){
      int e = tid + i*256;
      int m = e >> 4, kk = e & 15;
      float v = 0.f;
      if (k0 + kk < K) v = A[(size_t)(row0+m)*K + k0 + kk];
      As[kk][m] = v;
    }
    #pragma unroll
    for (int i = 0; i < 4; ++i){
      int e = tid + i*256;
      int n = e & 63, kb = e >> 6;
      float w = 0.f;
      if (k0 + kb < K && col0 + n < N) w = B[(size_t)(k0+kb)*ldb + col0 + n];
      Bs[kb][n] = w;
    }
    __syncthreads();
    #pragma unroll
    for (int kk = 0; kk < 16; ++kk){
      float a[8], bv[4];
      *(float4*)&a[0] = *(const float4*)&As[kk][tm*8];
      *(float4*)&a[4] = *(const float4*)&As[kk][tm*8+4];
      *(float4*)&bv[0] = *(const float4*)&Bs[kk][tn*4];
      #pragma unroll
      for (int i = 0; i < 8; ++i)
        #pragma unroll
        for (int j = 0; j < 4; ++j)
          acc[i][j] = fmaf(a[i], bv[j], acc[i][j]);
    }
    __syncthreads();
  }
  #pragma unroll
  for (int i = 0; i < 8; ++i){
    int r = row0 + tm*8 + i;
    #pragma unroll
    for (int j = 0; j < 4; ++j){
      int cc = col0 + tn*4 + j;
      if (cc < N) C[(size_t)r*N + cc] = acc[i][j] + (bias ? bias[cc] : 0.f);
    }
  }
}

// ---------------- weight permute for quad-gate encoder layout ----------------
__global__ void k_permW(const float* __restrict__ Wf, const float* __restrict__ bf,
                        const float* __restrict__ Wb, const float* __restrict__ bb,
                        float* __restrict__ WpF, float* __restrict__ WpB)
{
  int idx = blockIdx.x*256 + threadIdx.x;
  if (idx >= 2*357*400) return;
  int w = idx / (357*400), r = idx - w*(357*400);
  int j = r / 400, col = r - j*400;
  int src = (col & 3)*100 + (col >> 2);
  const float* W = w ? Wb : Wf; const float* bs = w ? bb : bf;
  float v = (j < 356) ? W[j*400 + src] : bs[src];
  (w ? WpB : WpF)[j*400 + col] = v;
}

// ---------------- standalone encoder (small-ws fallback path only) ----------------
__global__ __launch_bounds__(512, 1)
void k_encoder(const float* __restrict__ xprojF, const float* __restrict__ xprojB,
               const float* __restrict__ WpF, const float* __restrict__ WpB,
               const int* __restrict__ sig_len, float* __restrict__ memory,
               float* __restrict__ c0h0, int dirParam)
{
  int dir = dirParam, b = blockIdx.x;
  const float* xp = dir ? xprojB : xprojF;
  const float* Wp = dir ? WpB : WpF;
  int tid = threadIdx.x;
  bool act = tid < 400;
  int col = act ? tid : (tid - 400);
  int u = tid >> 2, gq = tid & 3;
  __shared__ __align__(16) float h2[2][104];
  float4 Uv[25];
  #pragma unroll
  for (int j4 = 0; j4 < 25; ++j4){
    Uv[j4].x = Wp[(256 + 4*j4 + 0)*400 + col];
    Uv[j4].y = Wp[(256 + 4*j4 + 1)*400 + col];
    Uv[j4].z = Wp[(256 + 4*j4 + 2)*400 + col];
    Uv[j4].w = Wp[(256 + 4*j4 + 3)*400 + col];
  }
  if (tid < 100) h2[0][tid] = 0.f;
  int len = sig_len[b];
  float c = 0.f, hfin = 0.f;
  int ta = dir ? (len-1) : 0;
  float xb0 = xp[((size_t)(b*T_ + ta))*400 + col];
  int tb_ = dir ? (len-2) : 1;
  float xb1 = xp[((size_t)(b*T_ + tb_))*400 + col];
  for (int step = 0; step < len; ++step){
    __syncthreads();
    int tn = dir ? (len-3-step) : (step+2);
    tn = tn < 0 ? 0 : (tn > T_-1 ? T_-1 : tn);
    float xn = xp[((size_t)(b*T_ + tn))*400 + col];
    const float* hb = h2[step & 1];
    float a0 = xb0, a1 = 0.f, a2 = 0.f, a3 = 0.f;
    #pragma unroll
    for (int j4 = 0; j4 < 25; ++j4){
      float4 h4 = *(const float4*)&hb[j4*4];
      a0 = fmaf(h4.x, Uv[j4].x, a0);
      a1 = fmaf(h4.y, Uv[j4].y, a1);
      a2 = fmaf(h4.z, Uv[j4].z, a2);
      a3 = fmaf(h4.w, Uv[j4].w, a3);
    }
    float z = (a0+a1)+(a2+a3);
    float v0 = z, v1 = __shfl_xor(z, 1);
    float v2 = __shfl_xor(v0, 2), v3 = __shfl_xor(v1, 2);
    float tA  = (gq&1) ? v1 : v0, tB  = (gq&1) ? v3 : v2;
    float tA2 = (gq&1) ? v0 : v1, tB2 = (gq&1) ? v2 : v3;
    float zi = (gq&2) ? tB  : tA;
    float zj = (gq&2) ? tB2 : tA2;
    float zf = (gq&2) ? tA  : tB;
    float zo = (gq&2) ? tA2 : tB2;
    c = c*sigf(zf + 1.f) + sigf(zi)*tanhf_(zj);
    float nh = tanhf_(c)*sigf(zo);
    hfin = nh;
    if (act && gq == 0){
      int t = dir ? (len-1-step) : step;
      h2[(step+1)&1][u] = nh;
      memory[((size_t)(b*T_ + t))*200 + dir*100 + u] = nh;
    }
    xb0 = xb1; xb1 = xn;
  }
  if (act && gq == 0){
    c0h0[b*400 + dir*100 + u]       = c;
    c0h0[b*400 + 200 + dir*100 + u] = hfin;
  }
  int total = (T_ - len)*100;
  for (int i = tid; i < total; i += 512){
    int t = len + i/100;
    int k = i - (i/100)*100;
    memory[((size_t)(b*T_ + t))*200 + dir*100 + k] = 0.f;
  }
}

// ---------------- decoder input gather ----------------
__global__ void k_gather(const float* __restrict__ emb, const int* __restrict__ labels,
                         float* __restrict__ dA)
{
  int idx = blockIdx.x*256 + threadIdx.x;
  int i = idx >> 6, e = idx & 63;
  dA[(size_t)i*64 + e] = emb[labels[i]*64 + e];
}

// ---------------- init: zero out + seq slots + flags ----------------
__global__ void k_dec_init(unsigned long long* __restrict__ nhb,
                           unsigned long long* __restrict__ parts,
                           unsigned* __restrict__ flags, unsigned fval,
                           float* __restrict__ out)
{
  int idx = blockIdx.x*256 + threadIdx.x;   // grid 192 -> 49152
  if (idx < B_*L_*6) out[idx] = 0.f;
  if (idx < B_*HD) nhb[idx] = 0ull;
  if (idx < B_*16*112) parts[idx] = 0ull;
  if (idx < 32) flags[idx] = fval;
}

// ================= fused encoder + keys + decoder, 512 threads =================
#define DEC_LDS 141440
#define TCH 128

__global__ __launch_bounds__(512, 1)
void k_fused(const float* __restrict__ xprojF, const float* __restrict__ xprojB,
             const float* __restrict__ WpF, const float* __restrict__ WpB,
             float* __restrict__ memG, float* c0h0,
             const float* __restrict__ W_mem, const float* __restrict__ W_attn,
             const float* __restrict__ decx, const float* __restrict__ W_dec,
             const float* __restrict__ W_out,
             const int* __restrict__ sig_len, const int* __restrict__ base_len,
             unsigned long long* nhb, unsigned long long* partials,
             unsigned* flags, int encInside,
             float* __restrict__ out)
{
  int blk = blockIdx.x;
  int b = (blk & 7) | (((blk >> 3) & 1) << 3);   // b's 16 blocks -> same XCD
  int g = blk >> 4;
  int tid = threadIdx.x;
  int u0 = g * 13;
  int nu = (HD - u0 < 13) ? (HD - u0) : 13;
  int t0 = g * TCH;

  extern __shared__ char smem[];
  uint2* keyP  = (uint2*)(smem);                 // [p<50][t<128+pad] stride 129 : 51600
  float* memAL = (float*)(smem + 51616);         // [128][50]
  float* Uld   = (float*)(smem + 77216);         // [250][52]; doubles as stg (51.2KB)
  float* Wa1s  = (float*)(smem + 129216);        // [13][50]
  float* WoutL = (float*)(smem + 131824);        // [50][6]
  float* nhF   = (float*)(smem + 133024);        // [208]
  float* spL   = (float*)(smem + 133856);        // [512]; doubles as encoder h2[2][104]
  float* wL    = (float*)(smem + 135904);        // [128]
  float* cpL   = (float*)(smem + 136416);        // [8][52] (7 used)
  float* apL   = (float*)(smem + 138080);        // [52]
  float* zp8   = (float*)(smem + 138288);        // [52][8]
  float* zpA   = (float*)(smem + 139952);        // [52][4]
  float* attnL = (float*)(smem + 140784);        // [52]
  float* SL    = (float*)(smem + 140992);        // [2]
  float* ctxR  = (float*)(smem + 141000);        // [52]
  float* apR   = (float*)(smem + 141208);        // [52]

  // ================= phase E: encoder (blocks g<2), 512-thread 1-col =================
  if (encInside && g < 2){
    int dir = g;
    const float* xp = dir ? xprojB : xprojF;
    const float* Wp = dir ? WpB : WpF;
    float* h2 = spL;                    // [2][104]
    bool act = tid < 400;
    int col = act ? tid : (tid - 400);
    int u = tid >> 2, gq = tid & 3;
    float4 Uv[25];
    #pragma unroll
    for (int j4 = 0; j4 < 25; ++j4){
      Uv[j4].x = Wp[(256 + 4*j4 + 0)*400 + col];
      Uv[j4].y = Wp[(256 + 4*j4 + 1)*400 + col];
      Uv[j4].z = Wp[(256 + 4*j4 + 2)*400 + col];
      Uv[j4].w = Wp[(256 + 4*j4 + 3)*400 + col];
    }
    if (tid < 104) { h2[tid] = 0.f; h2[104 + tid] = 0.f; }
    int len = sig_len[b];
    float c = 0.f, hfin = 0.f;
    int ta = dir ? (len-1) : 0;
    float xb0 = xp[((size_t)(b*T_ + ta))*400 + col];
    int tb_ = dir ? (len-2) : 1;
    float xb1 = xp[((size_t)(b*T_ + tb_))*400 + col];
    for (int step = 0; step < len; ++step){
      __syncthreads();
      int tn = dir ? (len-3-step) : (step+2);
      tn = tn < 0 ? 0 : (tn > T_-1 ? T_-1 : tn);
      float xn = xp[((size_t)(b*T_ + tn))*400 + col];
      const float* hb = h2 + (step & 1)*104;
      float a0 = xb0, a1 = 0.f, a2 = 0.f, a3 = 0.f;
      #pragma unroll
      for (int j4 = 0; j4 < 25; ++j4){
        float4 h4 = *(const float4*)&hb[j4*4];
        a0 = fmaf(h4.x, Uv[j4].x, a0);
        a1 = fmaf(h4.y, Uv[j4].y, a1);
        a2 = fmaf(h4.z, Uv[j4].z, a2);
        a3 = fmaf(h4.w, Uv[j4].w, a3);
      }
      float z = (a0+a1)+(a2+a3);
      float v0 = z, v1 = __shfl_xor(z, 1);
      float v2 = __shfl_xor(v0, 2), v3 = __shfl_xor(v1, 2);
      float tA  = (gq&1) ? v1 : v0, tB  = (gq&1) ? v3 : v2;
      float tA2 = (gq&1) ? v0 : v1, tB2 = (gq&1) ? v2 : v3;
      float zi = (gq&2) ? tB  : tA;
      float zj = (gq&2) ? tB2 : tA2;
      float zf = (gq&2) ? tA  : tB;
      float zo = (gq&2) ? tA2 : tB2;
      c = c*sigf(zf + 1.f) + sigf(zi)*tanhf_(zj);
      float nh = tanhf_(c)*sigf(zo);
      hfin = nh;
      if (act && gq == 0){
        int t = dir ? (len-1-step) : step;
        h2[((step+1)&1)*104 + u] = nh;
        memG[((size_t)(b*T_ + t))*200 + dir*100 + u] = nh;
      }
      xb0 = xb1; xb1 = xn;
    }
    if (act && gq == 0){
      c0h0[b*400 + dir*100 + u]       = c;
      c0h0[b*400 + 200 + dir*100 + u] = hfin;
    }
    int total = (T_ - len)*100;
    for (int i = tid; i < total; i += 512){
      int t = len + i/100;
      int k = i - (i/100)*100;
      memG[((size_t)(b*T_ + t))*200 + dir*100 + k] = 0.f;
    }
    __syncthreads();
    if (tid == 0){
      __builtin_amdgcn_fence(__ATOMIC_RELEASE, "agent");
      __hip_atomic_store(&flags[b*2 + dir], 1u,
                         __ATOMIC_RELAXED, __HIP_MEMORY_SCOPE_AGENT);
    }
  }

  // ================= wait for encoder-b done =================
  if (encInside){
    if (tid == 0){
      while (__hip_atomic_load(&flags[b*2+0], __ATOMIC_RELAXED, __HIP_MEMORY_SCOPE_AGENT) == 0u)
        __builtin_amdgcn_s_sleep(8);
      while (__hip_atomic_load(&flags[b*2+1], __ATOMIC_RELAXED, __HIP_MEMORY_SCOPE_AGENT) == 0u)
        __builtin_amdgcn_s_sleep(8);
      __builtin_amdgcn_fence(__ATOMIC_ACQUIRE, "agent");
    }
    __syncthreads();
  }

  // ================= keys + memA for this block's t-chunk =================
  unsigned* stg = (unsigned*)Uld;       // [t<128][p2<100] bf16x2
  for (int i = tid; i < TCH*100; i += 512){
    int t = i / 100, p2 = i - (i/100)*100;
    float2 mv = *(const float2*)&memG[((size_t)(b*T_ + t0 + t))*200 + 2*p2];
    stg[i] = bf16u(mv.x) | (bf16u(mv.y) << 16);
  }
  __syncthreads();
  // keys: one (t, d-quad) unit per iteration
  for (int i = tid; i < TCH*50; i += 512){
    int t = i / 50, q = i - (i/50)*50;
    int d = q*4;
    const unsigned* mrow = stg + t*100;
    float ax = 0.f, ay = 0.f, az = 0.f, aw = 0.f;
    for (int p2 = 0; p2 < 100; ++p2){
      unsigned mm = mrow[p2];
      float m0 = __uint_as_float(mm << 16);
      float m1 = __uint_as_float(mm & 0xFFFF0000u);
      float4 w0 = *(const float4*)&W_mem[(size_t)(2*p2)*200 + d];
      float4 w1 = *(const float4*)&W_mem[(size_t)(2*p2+1)*200 + d];
      ax = fmaf(m0, w0.x, fmaf(m1, w1.x, ax));
      ay = fmaf(m0, w0.y, fmaf(m1, w1.y, ay));
      az = fmaf(m0, w0.z, fmaf(m1, w1.z, az));
      aw = fmaf(m0, w0.w, fmaf(m1, w1.w, aw));
    }
    keyP[q*129 + t] = make_uint2(bf16u(ax) | (bf16u(ay) << 16),
                                 bf16u(az) | (bf16u(aw) << 16));
  }
  // memA: one (t, d) unit per iteration
  for (int i = tid; i < TCH*50; i += 512){
    int t = i / 50, d = i - (i/50)*50;
    const unsigned* mrow = stg + t*100;
    float acc = 0.f;
    for (int p2 = 0; p2 < 100; ++p2){
      unsigned mm = mrow[p2];
      float m0 = __uint_as_float(mm << 16);
      float m1 = __uint_as_float(mm & 0xFFFF0000u);
      acc = fmaf(m0, W_attn[(size_t)(200 + 2*p2)*50 + d],
            fmaf(m1, W_attn[(size_t)(201 + 2*p2)*50 + d], acc));
    }
    memAL[t*50 + d] = acc;
  }
  __syncthreads();     // stg reads done before Uld overwrite

  // ================= one-time decoder fills =================
  for (int i = tid; i < 250*52; i += 512){
    int j = i / 52, o_ = i - (i/52)*52;
    int uu = o_ >> 2, gg = o_ & 3;
    Uld[i] = (uu < nu) ? W_dec[(size_t)(64 + j)*800 + gg*200 + u0 + uu] : 0.f;
  }
  for (int i = tid; i < 13*50; i += 512){
    int uw = i / 50, d = i - (i/50)*50;
    Wa1s[i] = (uw < nu) ? W_attn[(size_t)(u0 + uw)*50 + d] : 0.f;
  }
  for (int i = tid; i < 300; i += 512) WoutL[i] = W_out[i];
  if (tid < 52) attnL[tid] = 0.f;
  if (tid < 8)  nhF[200 + tid] = 0.f;
  float creg = (tid < nu) ? c0h0[b*400 + u0 + tid] : 0.f;
  int len = sig_len[b];
  int Lb  = base_len[b];
  unsigned long long* nhB = nhb + (size_t)b*HD;
  __syncthreads();

  // ---- pre-loop: nhF = h0 ----
  if (tid < 50) *(float4*)&nhF[tid*4] = *(const float4*)&c0h0[b*400 + 200 + tid*4];
  __syncthreads();
  int o  = tid - (tid/52)*52;          // gemv layouts
  int jc8 = tid / 52;                  // 0..7 for tid<416 (zh 25-row chunks)
  int jc4 = tid / 52;                  // 0..3 for tid<208 (attn 13-row chunks)
  float dcx = 0.f;
  // zh(0) partials into zp8 + dcx(0)
  if (tid < 416){
    const float* Ub = &Uld[(50 + jc8*25)*52 + o];
    const float* hp = &nhF[jc8*25];
    float zh = 0.f;
    #pragma unroll
    for (int j = 0; j < 25; ++j) zh = fmaf(hp[j], Ub[(size_t)j*52], zh);
    zp8[o*8 + jc8] = zh;
    if (tid < 52) dcx = decx[((size_t)(b*L_))*800 + (o&3)*200 + u0 + (o>>2)];
  }
  __syncthreads();

  for (int l = 0; l < Lb; ++l){
    unsigned seq = (unsigned)(l + 1);
    // ---- A: za gemv (attn rows, 4 chunks); g1 writes out(l-1)
    if (tid < 208){
      float z = zp8[o*8 + 2*jc4] + zp8[o*8 + 2*jc4 + 1] + ((jc4 == 0) ? dcx : 0.f);
      const float* Ub = &Uld[(jc4*13)*52 + o];
      const float* ap_ = &attnL[jc4*13];
      int cnt = (jc4 < 3) ? 13 : 11;
      for (int j = 0; j < cnt; ++j) z = fmaf(ap_[j], Ub[(size_t)j*52], z);
      zpA[o*4 + jc4] = z;
    } else if (g == 1 && l > 0 && tid >= 208 && tid < 214){
      int j = tid - 208;
      float o_ = 0.f;
      for (int d = 0; d < AT; ++d) o_ = fmaf(attnL[d], WoutL[d*6 + j], o_);
      out[((size_t)(b*L_ + (l-1)))*6 + j] = o_;
    }
    __syncthreads();
    // ---- B: combine + activation; publish nh slice
    if (tid < nu){
      const float* zz = &zpA[16*tid];
      float zi = (zz[0]+zz[1])+(zz[2]+zz[3]);
      float zj = (zz[4]+zz[5])+(zz[6]+zz[7]);
      float zf = (zz[8]+zz[9])+(zz[10]+zz[11]);
      float zo = (zz[12]+zz[13])+(zz[14]+zz[15]);
      float c = creg;
      c = c*sigf(zf + 1.f) + sigf(zi)*tanhf_(zj);
      creg = c;
      float nh = tanhf_(c)*sigf(zo);
      __hip_atomic_store(&nhB[u0 + tid], pkvs(nh, seq),
                         __ATOMIC_RELAXED, __HIP_MEMORY_SCOPE_AGENT);
    }
    // ---- C: poll full nh vector
    if (tid < HD){
      unsigned long long v;
      do {
        v = __hip_atomic_load(&nhB[tid], __ATOMIC_RELAXED, __HIP_MEMORY_SCOPE_AGENT);
      } while ((unsigned)(v >> 32) != seq);
      nhF[tid] = __uint_as_float((unsigned)v);
    }
    __syncthreads();
    // ---- D: scores, 4-way split over key range
    {
      int t = tid & 127, dh = tid >> 7;            // dh wave-uniform
      int pstart = (dh < 2) ? dh*13 : 26 + (dh-2)*12;
      int pcnt   = (dh < 2) ? 13 : 12;
      const uint2* kp = &keyP[pstart*129 + t];
      const float4* nf = (const float4*)nhF + pstart;
      float s0 = 0.f, s1 = 0.f;
      for (int q = 0; q < pcnt; ++q){
        uint2 kk = kp[(size_t)q*129];
        float4 nv = nf[q];
        s0 = fmaf(nv.x, __uint_as_float(kk.x << 16), s0);
        s1 = fmaf(nv.y, __uint_as_float(kk.x & 0xFFFF0000u), s1);
        s0 = fmaf(nv.z, __uint_as_float(kk.y << 16), s0);
        s1 = fmaf(nv.w, __uint_as_float(kk.y & 0xFFFF0000u), s1);
      }
      spL[tid] = s0 + s1;
    }
    __syncthreads();
    // ---- E: w=exp ; ap gemv
    if (tid < 128){
      float s = (spL[tid] + spL[tid + 128]) + (spL[tid + 256] + spL[tid + 384]);
      float w = 0.f;
      if (t0 + tid < len){ s = fminf(60.f, fmaxf(-60.f, s)); w = __expf(s); }
      wL[tid] = w;
    } else if (tid < 178){
      int d = tid - 128;
      float a = 0.f;
      #pragma unroll
      for (int uw = 0; uw < 13; ++uw) a = fmaf(nhF[u0 + uw], Wa1s[uw*50 + d], a);
      apL[d] = a;
    }
    __syncthreads();
    // ---- F: ctx partials (7 chunks of 18/20 t) + S reduce (wave 7)
    if (tid >= 448){
      float v = wL[tid - 448] + wL[tid - 384];
      #pragma unroll
      for (int off = 32; off > 0; off >>= 1) v += __shfl_down(v, off);
      if (tid == 448) SL[0] = v;
    } else {
      int tc = tid >> 6, d = tid & 63;             // tc 0..6
      if (d < 50){
        int tlo = tc*18, thi = (tc == 6) ? 128 : tlo + 18;
        float a = 0.f;
        for (int t = tlo; t < thi; ++t) a = fmaf(wL[t], memAL[t*50 + d], a);
        cpL[tc*52 + d] = a;
      }
    }
    __syncthreads();
    // ---- G: publish partials; zh(l+1)+dcx(l+1); poll-reduce partials
    {
      unsigned long long* pb = partials + (size_t)(b*16 + g)*112;
      if (tid < 50){
        float p0 = 0.f;
        #pragma unroll
        for (int k = 0; k < 7; ++k) p0 += cpL[k*52 + tid];
        __hip_atomic_store(&pb[tid], pkvs(p0, seq),
                           __ATOMIC_RELAXED, __HIP_MEMORY_SCOPE_AGENT);
      } else if (tid < 100)
        __hip_atomic_store(&pb[tid], pkvs(apL[tid - 50], seq),
                           __ATOMIC_RELAXED, __HIP_MEMORY_SCOPE_AGENT);
      else if (tid == 100)
        __hip_atomic_store(&pb[100], pkvs(SL[0], seq),
                           __ATOMIC_RELAXED, __HIP_MEMORY_SCOPE_AGENT);
    }
    if (tid < 416){
      const float* Ub = &Uld[(50 + jc8*25)*52 + o];
      const float* hp = &nhF[jc8*25];
      float zh = 0.f;
      #pragma unroll
      for (int j = 0; j < 25; ++j) zh = fmaf(hp[j], Ub[(size_t)j*52], zh);
      zp8[o*8 + jc8] = zh;
      if (tid < 52 && l+1 < Lb)
        dcx = decx[((size_t)(b*L_ + (l+1)))*800 + (o&3)*200 + u0 + (o>>2)];
    }
    if (tid < 101){
      const unsigned long long* base = partials + (size_t)b*16*112 + tid;
      unsigned long long v[16];
      #pragma unroll
      for (int gq2 = 0; gq2 < 16; ++gq2)
        v[gq2] = __hip_atomic_load(&base[gq2*112], __ATOMIC_RELAXED, __HIP_MEMORY_SCOPE_AGENT);
      #pragma unroll
      for (int gq2 = 0; gq2 < 16; ++gq2)
        while ((unsigned)(v[gq2] >> 32) != seq)
          v[gq2] = __hip_atomic_load(&base[gq2*112], __ATOMIC_RELAXED, __HIP_MEMORY_SCOPE_AGENT);
      float acc = 0.f;
      #pragma unroll
      for (int gq2 = 0; gq2 < 16; ++gq2) acc += __uint_as_float((unsigned)v[gq2]);
      if (tid < 50) ctxR[tid] = acc;
      else if (tid < 100) apR[tid - 50] = acc;
      else SL[1] = acc;
    }
    __syncthreads();
    // ---- H: attn(l)
    if (tid < 50) attnL[tid] = fmaf(ctxR[tid], rcp_(SL[1]), apR[tid]);
    __syncthreads();
  }
  // tail: out(Lb-1)
  if (g == 1 && tid < 6){
    float o_ = 0.f;
    for (int d = 0; d < AT; ++d) o_ = fmaf(attnL[d], WoutL[d*6 + tid], o_);
    out[((size_t)(b*L_ + (Lb-1)))*6 + tid] = o_;
  }
}

extern "C" void kernel_launch(void* const* d_in, const int* in_sizes, int n_in,
                              void* d_out, int out_size, void* d_ws, size_t ws_size,
                              hipStream_t stream)
{
  const float* signals   = (const float*)d_in[0];
  const float* embeddings= (const float*)d_in[1];
  const float* conv1_k   = (const float*)d_in[2];
  const float* conv1a_k  = (const float*)d_in[3];
  const float* conv1a_b  = (const float*)d_in[4];
  const float* conv2_k   = (const float*)d_in[5];
  const float* conv3_k   = (const float*)d_in[6];
  const float* W_fwd     = (const float*)d_in[7];
  const float* b_fwd     = (const float*)d_in[8];
  const float* W_bwd     = (const float*)d_in[9];
  const float* b_bwd     = (const float*)d_in[10];
  const float* W_dec     = (const float*)d_in[11];
  const float* b_dec     = (const float*)d_in[12];
  const float* W_mem     = (const float*)d_in[13];
  const float* W_attn    = (const float*)d_in[14];
  const float* W_out     = (const float*)d_in[15];
  const int*   labels    = (const int*)d_in[16];
  const int*   sig_len   = (const int*)d_in[17];
  const int*   base_len  = (const int*)d_in[18];
  float* out = (float*)d_out;
  char* ws = (char*)d_ws;

  const size_t o_c0h0     = 4096;
  const size_t o_nhbuf    = 32768;
  const size_t o_partials = 65536;
  const size_t o_flags    = 458752;
  const size_t o_WpF      = 589824;
  const size_t o_WpB      = 1161024;
  const size_t o_feat     = 4194304;
  const size_t o_mem      = o_feat + 33554432;
  const size_t o_X1       = o_mem + 26214400;
  const size_t o_X2       = o_X1 + 52428800;

  bool bigws = (ws_size >= o_X2 + 52428800);

  float* E      = (float*)(ws);
  float* c0h0   = (float*)(ws + o_c0h0);
  unsigned long long* nhbuf = (unsigned long long*)(ws + o_nhbuf);
  unsigned long long* parts = (unsigned long long*)(ws + o_partials);
  unsigned* flags = (unsigned*)(ws + o_flags);
  float* WpF    = (float*)(ws + o_WpF);
  float* WpB    = (float*)(ws + o_WpB);
  float* feat   = (float*)(ws + o_feat);
  float* memory = (float*)(ws + o_mem);
  float* xprojF = (float*)(ws + o_X1);
  float* xprojB = bigws ? (float*)(ws + o_X2) : xprojF;
  float* decxA  = (float*)(ws + o_feat);                 // overlay (feat dead)
  float* decx   = (float*)(ws + o_feat + 4194304);       // overlay (feat dead)

  k_prep<<<1, 768, 0, stream>>>(conv1_k, conv1a_k, conv2_k, conv3_k, E);
  k_feat<<<8192, 256, 0, stream>>>(signals, E, conv1a_b, feat);
  k_permW<<<1116, 256, 0, stream>>>(W_fwd, b_fwd, W_bwd, b_bwd, WpF, WpB);

  dim3 gx(256, 7);
  if (bigws){
    k_gemm<<<gx, 256, 0, stream>>>(feat, WpF, WpF + 356*400, xprojF, 32768, 400, 256, 400);
    k_gemm<<<gx, 256, 0, stream>>>(feat, WpB, WpB + 356*400, xprojB, 32768, 400, 256, 400);
  } else {
    k_gemm<<<gx, 256, 0, stream>>>(feat, WpF, WpF + 356*400, xprojF, 32768, 400, 256, 400);
    k_encoder<<<16, 512, 0, stream>>>(xprojF, xprojF, WpF, WpB, sig_len, memory, c0h0, 0);
    k_gemm<<<gx, 256, 0, stream>>>(feat, WpB, WpB + 356*400, xprojF, 32768, 400, 256, 400);
    k_encoder<<<16, 512, 0, stream>>>(xprojF, xprojF, WpF, WpB, sig_len, memory, c0h0, 1);
  }

  // feat dead now -> decxA/decx overlay safe
  k_gather<<<2048, 256, 0, stream>>>(embeddings, labels, decxA);
  k_gemm<<<dim3(64, 13), 256, 0, stream>>>(decxA, W_dec, b_dec, decx, 8192, 800, 64, 800);
  k_dec_init<<<192, 256, 0, stream>>>(nhbuf, parts, flags, bigws ? 0u : 1u, out);

  hipFuncSetAttribute(reinterpret_cast<const void*>(k_fused),
                      hipFuncAttributeMaxDynamicSharedMemorySize, DEC_LDS);
  k_fused<<<256, 512, DEC_LDS, stream>>>(xprojF, xprojB, WpF, WpB,
                                         memory, c0h0, W_mem, W_attn,
                                         decx, W_dec, W_out,
                                         sig_len, base_len,
                                         nhbuf, parts, flags, bigws ? 1 : 0,
                                         out);
}